// Round 15
// baseline (423.490 us; speedup 1.0000x reference)
//
#include <hip/hip_runtime.h>
#include <math.h>

#define DIMC 384
#define NHD  6
#define HD   64
#define WSZ  14
#define NTOK 196
#define NWIN 200
#define NWH  1200
#define MWIN 39200
#define MX   32768
#define MLPD 1536

typedef short short8 __attribute__((ext_vector_type(8)));
typedef float f32x4 __attribute__((ext_vector_type(4)));
typedef float f32x16 __attribute__((ext_vector_type(16)));

__device__ __forceinline__ unsigned short f2bf(float f) {
  unsigned int u = __float_as_uint(f);
  u = (u + 0x7fffu + ((u >> 16) & 1u)) >> 16;
  return (unsigned short)u;
}
__device__ __forceinline__ float bf2f(unsigned int u) {
  return __uint_as_float(u << 16);
}
__device__ __forceinline__ unsigned int pkbf(float a, float b) {
  unsigned int r; asm("v_cvt_pk_bf16_f32 %0, %1, %2" : "=v"(r) : "v"(a), "v"(b)); return r;
}
// tanh-GELU (|err| <= ~3e-3 abs; well under tolerance here)
__device__ __forceinline__ float gelu_t(float x) {
  float z = 1.5957691216057308f * (x + 0.044715f * x * x * x);
  float e = __expf(z);
  float th = 1.f - 2.f * __builtin_amdgcn_rcpf(e + 1.f);
  return 0.5f * x * (1.f + th);
}

typedef const __attribute__((address_space(1))) unsigned int* gptr_t;
typedef __attribute__((address_space(3))) unsigned int* lptr_t;
__device__ __forceinline__ void gload16(const unsigned short* g, unsigned short* l) {
  __builtin_amdgcn_global_load_lds((gptr_t)(const void*)g, (lptr_t)(void*)l, 16, 0, 0);
}

// ---------- merged pre: LN1+window (4 tokens/block) THEN prep segments ----------
#define LN1BLKS 9800         // 39200 tokens / 4
#define SEG0 442368          // qkvwT  (K=384,  N=1152)
#define SEG1 589824          // projwT (K=384,  N=384)
#define SEG2 1179648         // fc1wT  (K=384,  N=1536)
#define SEG3 1769472         // fc2wT  (K=1536, N=384)
#define SEG4 1773568         // relcat (4096)
#define SEG5 2003968         // vpad   (76800*3 int2 writes)
__global__ __launch_bounds__(256) void pre_kernel(
    const float* __restrict__ x, const float* __restrict__ ln1w, const float* __restrict__ ln1b,
    const float* __restrict__ qkvw, const float* __restrict__ projw,
    const float* __restrict__ fc1w, const float* __restrict__ fc2w,
    const float* __restrict__ relh, const float* __restrict__ relw,
    unsigned short* __restrict__ xw,
    unsigned short* __restrict__ qkvwT, unsigned short* __restrict__ projwT,
    unsigned short* __restrict__ fc1wT, unsigned short* __restrict__ fc2wT,
    unsigned short* __restrict__ relcat, unsigned short* __restrict__ vT) {
  const int blk = blockIdx.x;
  if (blk < LN1BLKS) {
    int t = blk * 4 + (threadIdx.x >> 6);
    int lane = threadIdx.x & 63;
    int win = t / NTOK, p = t - win * NTOK;
    int bb = win / 25, rem = win - bb * 25;
    int wi = rem / 5, wj = rem - wi * 5;
    int i = p / WSZ, j = p - i * WSZ;
    int r = wi * WSZ + i, c = wj * WSZ + j;
    unsigned short* o = xw + (size_t)t * DIMC;
    if (r >= 64 || c >= 64) {
      #pragma unroll
      for (int q = 0; q < 6; q++) o[lane + q * 64] = 0;
      return;
    }
    const float* xr = x + (((size_t)bb * 64 + r) * 64 + c) * DIMC;
    float v[6]; float s = 0.f, s2 = 0.f;
    #pragma unroll
    for (int q = 0; q < 6; q++) { float f = xr[lane + q * 64]; v[q] = f; s += f; s2 += f * f; }
    #pragma unroll
    for (int off = 32; off; off >>= 1) { s += __shfl_xor(s, off); s2 += __shfl_xor(s2, off); }
    float mean = s * (1.f / DIMC);
    float var  = s2 * (1.f / DIMC) - mean * mean;
    float rstd = rsqrtf(var + 1e-5f);
    #pragma unroll
    for (int q = 0; q < 6; q++) {
      int d = lane + q * 64;
      o[d] = f2bf((v[q] - mean) * rstd * ln1w[d] + ln1b[d]);
    }
    return;
  }
  int id = (blk - LN1BLKS) * 256 + threadIdx.x;
  if (id < SEG0) {
    int n = id / 384, k = id - n * 384;
    qkvwT[id] = f2bf(qkvw[(size_t)k * 1152 + n]);
  } else if (id < SEG1) {
    id -= SEG0;
    int n = id / 384, k = id - n * 384;
    projwT[id] = f2bf(projw[(size_t)k * 384 + n]);
  } else if (id < SEG2) {
    id -= SEG1;
    int n = id / 384, k = id - n * 384;
    fc1wT[id] = f2bf(fc1w[(size_t)k * 1536 + n]);
  } else if (id < SEG3) {
    id -= SEG2;
    int n = id / 1536, k = id - n * 1536;
    fc2wT[id] = f2bf(fc2w[(size_t)k * 384 + n]);
  } else if (id < SEG4) {
    id -= SEG3;
    int rc = id >> 6, d = id & 63;
    float v = 0.f;
    if (rc < 27) v = relh[rc * 64 + d] * 8.f;
    else if (rc < 54) v = relw[(rc - 27) * 64 + d] * 8.f;
    relcat[id] = f2bf(v);
  } else if (id < SEG5) {
    id -= SEG4;
    int row = id / 3, part = id - row * 3;
    *(int2*)(vT + (size_t)row * 208 + 196 + part * 4) = make_int2(0, 0);
  }
}

// ---------- LN2: 4 rows per 256-thr block, x2 in bf16 ----------
__global__ __launch_bounds__(256) void ln2_kernel(const unsigned short* __restrict__ x2b,
    const float* __restrict__ w, const float* __restrict__ b, unsigned short* __restrict__ h2) {
  int t = blockIdx.x * 4 + (threadIdx.x >> 6);
  int lane = threadIdx.x & 63;
  const unsigned short* xr = x2b + (size_t)t * DIMC;
  unsigned short* o = h2 + (size_t)t * DIMC;
  float v[6]; float s = 0.f, s2 = 0.f;
  #pragma unroll
  for (int q = 0; q < 6; q++) { float f = bf2f(xr[lane + q * 64]); v[q] = f; s += f; s2 += f * f; }
  #pragma unroll
  for (int off = 32; off; off >>= 1) { s += __shfl_xor(s, off); s2 += __shfl_xor(s2, off); }
  float mean = s * (1.f / DIMC);
  float var  = s2 * (1.f / DIMC) - mean * mean;
  float rstd = rsqrtf(var + 1e-5f);
  #pragma unroll
  for (int q = 0; q < 6; q++) {
    int d = lane + q * 64;
    o[d] = f2bf((v[q] - mean) * rstd * w[d] + b[d]);
  }
}

// ---------- bf16 MFMA GEMM: TM x 128 tile, 2-buffer stage pipeline (r8-proven schedule),
// swizzled LDS (0 conflicts), XCD remap. TM=256: wave=128x64, halves block count. ----------
// EPI 0: qkv  -> q,k bf16 packed; v transposed scatter
// EPI 1: proj -> (acc+bias+x_f32) -> x2 bf16 packed
// EPI 2: fc1  -> bias + gelu -> hidden bf16 packed
// EPI 3: fc2  -> bias + x2(bf16) residual -> d_out fp32
template <int EPI, int TM>
__global__ __launch_bounds__(256) void gemm_kernel(
    const unsigned short* __restrict__ A, const unsigned short* __restrict__ WT,
    int Mrows, int Kd,
    const float* __restrict__ bias,
    const float* __restrict__ addinf, const unsigned short* __restrict__ addinb,
    float* __restrict__ outf, unsigned short* __restrict__ outb,
    unsigned short* __restrict__ outb2) {
  constexpr int NFI = TM / 32;             // fragments per wave in M
  __shared__ unsigned short As[2][TM * 32];
  __shared__ unsigned short Bs[2][128 * 32];
  const int nwg = gridDim.x * gridDim.y;
  const int flat = blockIdx.y * gridDim.x + blockIdx.x;
  const int xcd = flat & 7, q_ = nwg >> 3, r_ = nwg & 7;
  const int wg = (xcd < r_ ? xcd * (q_ + 1) : r_ * (q_ + 1) + (xcd - r_) * q_) + (flat >> 3);
  const int bx = wg / gridDim.y, by = wg - bx * gridDim.y;
  const int row0 = bx * TM, col0 = by * 128;
  const int tid = threadIdx.x;
  const int l = tid & 63, wid = tid >> 6;
  const int fr = l & 15, fk = (l >> 4) * 8;
  const int wr = (wid >> 1) * (TM / 2), wc = (wid & 1) * 64;
  const int sr = l >> 2, sc = (l & 3) * 8;
  const int scs = sc ^ (((sr >> 1) & 3) << 3);
  const int rsw = ((fr >> 1) & 3) << 3;
  f32x4 acc[NFI][4] = {};
  const unsigned short* ap = A + (size_t)row0 * Kd;
  const unsigned short* bp = WT + (size_t)col0 * Kd;
  const int nt = Kd >> 5;

  auto stage = [&](int t, int b) {
    const int k0 = t * 32;
    #pragma unroll
    for (int j = 0; j < TM / 64; j++) {
      int chunk = j * 4 + wid;
      gload16(ap + (size_t)(chunk * 16 + sr) * Kd + k0 + scs, &As[b][chunk * 512]);
    }
    #pragma unroll
    for (int j = 0; j < 2; j++) {
      int chunk = j * 4 + wid;
      gload16(bp + (size_t)(chunk * 16 + sr) * Kd + k0 + scs, &Bs[b][chunk * 512]);
    }
  };
  stage(0, 0);
  __syncthreads();
  int cur = 0;
  for (int t = 0; t < nt; ++t) {
    if (t + 1 < nt) stage(t + 1, cur ^ 1);
    short8 a[NFI], b[4];
    #pragma unroll
    for (int fi = 0; fi < NFI; fi++)
      a[fi] = *(const short8*)&As[cur][(wr + fi * 16 + fr) * 32 + (fk ^ rsw)];
    #pragma unroll
    for (int fj = 0; fj < 4; fj++)
      b[fj] = *(const short8*)&Bs[cur][(wc + fj * 16 + fr) * 32 + (fk ^ rsw)];
    __builtin_amdgcn_s_setprio(1);
    #pragma unroll
    for (int fi = 0; fi < NFI; fi++)
      #pragma unroll
      for (int fj = 0; fj < 4; fj++)
        acc[fi][fj] = __builtin_amdgcn_mfma_f32_16x16x32_bf16(b[fj], a[fi], acc[fi][fj], 0, 0, 0);
    __builtin_amdgcn_s_setprio(0);
    __syncthreads();   // drains the just-issued prefetch + barriers (r8 semantics)
    cur ^= 1;
  }
  #pragma unroll
  for (int fi = 0; fi < NFI; fi++) {
    const int gr = row0 + wr + fi * 16 + fr;
    if (gr >= Mrows) continue;
    int wv_ = 0, p = 0, valid = 1; size_t pixbase = 0;
    if (EPI == 0 || EPI == 1) { wv_ = gr / NTOK; p = gr - wv_ * NTOK; }
    if (EPI == 1) {
      int bb = wv_ / 25, rem2 = wv_ - bb * 25;
      int wi = rem2 / 5, wj = rem2 - wi * 5;
      int i = p / WSZ, j = p - i * WSZ;
      int rr = wi * WSZ + i, cc = wj * WSZ + j;
      valid = (rr < 64) && (cc < 64);
      pixbase = (((size_t)bb * 64 + rr) * 64 + cc) * DIMC;
    }
    #pragma unroll
    for (int fj = 0; fj < 4; fj++) {
      const int gcb = col0 + wc + fj * 16 + (l >> 4) * 4;
      f32x4 v = acc[fi][fj];
      float4 bv = *(const float4*)&bias[gcb];
      float t0 = v[0] + bv.x, t1 = v[1] + bv.y, t2 = v[2] + bv.z, t3 = v[3] + bv.w;
      if (EPI == 0) {
        int s = gcb / 384, rem = gcb - s * 384;
        int hh = rem >> 6, d0 = gcb & 63;
        int whh = wv_ * NHD + hh;
        if (s == 0) { t0 *= 0.125f; t1 *= 0.125f; t2 *= 0.125f; t3 *= 0.125f; }
        if (s < 2) {
          *(int2*)&outb[((size_t)s * NWH + whh) * (NTOK * 64) + p * 64 + d0] =
              make_int2((int)pkbf(t0, t1), (int)pkbf(t2, t3));
        } else {
          unsigned short* vb = outb2 + ((size_t)whh * 64 + d0) * 208 + p;
          vb[0] = f2bf(t0); vb[208] = f2bf(t1); vb[416] = f2bf(t2); vb[624] = f2bf(t3);
        }
      } else if (EPI == 1) {
        if (valid) {
          size_t idx = pixbase + gcb;
          float4 ad = *(const float4*)&addinf[idx];
          *(int2*)&outb[idx] = make_int2((int)pkbf(t0 + ad.x, t1 + ad.y),
                                         (int)pkbf(t2 + ad.z, t3 + ad.w));
        }
      } else if (EPI == 2) {
        *(int2*)&outb[(size_t)gr * MLPD + gcb] =
            make_int2((int)pkbf(gelu_t(t0), gelu_t(t1)), (int)pkbf(gelu_t(t2), gelu_t(t3)));
      } else {
        size_t idx = (size_t)gr * DIMC + gcb;
        int2 adp = *(const int2*)&addinb[idx];
        unsigned int u0 = (unsigned int)adp.x, u1 = (unsigned int)adp.y;
        float4 o = make_float4(t0 + bf2f(u0 & 0xffffu), t1 + bf2f(u0 >> 16),
                               t2 + bf2f(u1 & 0xffffu), t3 + bf2f(u1 >> 16));
        *(float4*)&outf[idx] = o;
      }
    }
  }
}

// ---------- 32x32 MFMA attention: in-register P, defer-max online softmax ----------
template <bool TAIL>
__device__ __forceinline__ void attn_chunk(
    int kk, int l31, int hi,
    const unsigned short* __restrict__ kg,
    const unsigned short* __restrict__ VT,
    const short8* qf, const short8* qrel,
    f32x16& olo, f32x16& ohi_, float& m_reg, float& s_run) {
  int key = kk * 32 + l31;
  int keyc = (TAIL && key > 195) ? 195 : key;
  f32x16 S = {};
  __builtin_amdgcn_s_setprio(1);
  #pragma unroll
  for (int m = 0; m < 4; m++) {
    short8 kf = *(const short8*)(kg + (size_t)keyc * 64 + m * 16 + hi * 8);
    S = __builtin_amdgcn_mfma_f32_32x32x16_bf16(kf, qf[m], S, 0, 0, 0);
  }
  {
    int ki = keyc / 14, kj = keyc - ki * 14;
    #pragma unroll
    for (int m2 = 0; m2 < 2; m2++) {
      short8 kh;
      #pragma unroll
      for (int j = 0; j < 8; j++) {
        int cc = m2 * 16 + hi * 8 + j;
        kh[j] = (short)((cc == ki || cc == 14 + kj) ? 0x3F80 : 0);
      }
      S = __builtin_amdgcn_mfma_f32_32x32x16_bf16(kh, qrel[m2], S, 0, 0, 0);
    }
  }
  __builtin_amdgcn_s_setprio(0);
  float pmax = -3e38f;
  #pragma unroll
  for (int r = 0; r < 16; r++) {
    if (TAIL) {
      int krow = kk * 32 + (r & 3) + 8 * (r >> 2) + 4 * hi;
      if (krow >= 196) S[r] = -3e38f;
    }
    pmax = fmaxf(pmax, S[r]);
  }
  pmax = fmaxf(pmax, __shfl_xor(pmax, 32));
  if (__any(pmax > m_reg + 8.f)) {
    float m_new = fmaxf(m_reg, pmax);
    float fac = __expf(m_reg - m_new);
    m_reg = m_new;
    s_run *= fac;
    #pragma unroll
    for (int r = 0; r < 16; r++) {
      int qr = (r & 3) + 8 * (r >> 2) + 4 * hi;
      float fr_ = __shfl(fac, qr);
      olo[r] *= fr_; ohi_[r] *= fr_;
    }
  }
  float psum = 0.f;
  #pragma unroll
  for (int r = 0; r < 16; r++) { S[r] = __expf(S[r] - m_reg); psum += S[r]; }
  s_run += psum;
  unsigned int pk[8];
  #pragma unroll
  for (int t = 0; t < 8; t++) pk[t] = pkbf(S[2 * t], S[2 * t + 1]);
  #pragma unroll
  for (int m2 = 0; m2 < 2; m2++) {
    int b_ = m2 * 4;
    unsigned int x0 = (unsigned int)__shfl_xor((int)pk[b_ + 0], 32);
    unsigned int x1 = (unsigned int)__shfl_xor((int)pk[b_ + 1], 32);
    unsigned int x2 = (unsigned int)__shfl_xor((int)pk[b_ + 2], 32);
    unsigned int x3 = (unsigned int)__shfl_xor((int)pk[b_ + 3], 32);
    unsigned int au[4];
    au[0] = hi ? x2 : pk[b_ + 0];
    au[1] = hi ? x3 : pk[b_ + 1];
    au[2] = hi ? pk[b_ + 2] : x0;
    au[3] = hi ? pk[b_ + 3] : x1;
    short8 pa; __builtin_memcpy(&pa, au, 16);
    int kb = kk * 32 + m2 * 16 + hi * 8;
    if (TAIL && kb > 208) kb = 208;
    short8 vblo = *(const short8*)&VT[l31 * 216 + kb];
    short8 vbhi = *(const short8*)&VT[(32 + l31) * 216 + kb];
    __builtin_amdgcn_s_setprio(1);
    olo  = __builtin_amdgcn_mfma_f32_32x32x16_bf16(pa, vblo, olo, 0, 0, 0);
    ohi_ = __builtin_amdgcn_mfma_f32_32x32x16_bf16(pa, vbhi, ohi_, 0, 0, 0);
    __builtin_amdgcn_s_setprio(0);
  }
}

__global__ __launch_bounds__(256) void attn32_kernel(
    const unsigned short* __restrict__ qk_g,
    const unsigned short* __restrict__ vT_g,
    const unsigned short* __restrict__ relcat,
    unsigned short* __restrict__ attnout) {
  __shared__ __align__(16) unsigned short VT[64 * 216];
  __shared__ __align__(16) unsigned short RELB[4][2048];
  const int wh = blockIdx.x, y = blockIdx.y;
  const int w = wh / NHD, h = wh - w * NHD;
  const int tid = threadIdx.x;
  const unsigned short* vrow = vT_g + (size_t)wh * 64 * 208;
  for (int e = tid; e < 64 * 27; e += 256) {
    int d = e / 27, c = e - d * 27;
    int4 val = {0, 0, 0, 0};
    if (c < 26) val = *(const int4*)(vrow + d * 208 + c * 8);
    *(int4*)&VT[d * 216 + c * 8] = val;
  }
  __syncthreads();
  const int l = tid & 63, wv = tid >> 6;
  const int l31 = l & 31, hi = l >> 5;
  unsigned short* RB = &RELB[wv][0];
  const unsigned short* qg = qk_g + (size_t)wh * (NTOK * 64);
  const unsigned short* kg = qk_g + (size_t)(NWH + wh) * (NTOK * 64);

  const int tbeg = y ? 4 : 0, tend = y ? 7 : 4;
  for (int tile = tbeg + wv; tile < tend; tile += 4) {
    const int q0 = tile * 32;
    int qrow = q0 + l31; if (qrow > 195) qrow = 195;
    short8 qf[4];
    #pragma unroll
    for (int m = 0; m < 4; m++)
      qf[m] = *(const short8*)(qg + (size_t)qrow * 64 + m * 16 + hi * 8);
    #pragma unroll
    for (int rt = 0; rt < 2; rt++) {
      f32x16 cr = {};
      __builtin_amdgcn_s_setprio(1);
      #pragma unroll
      for (int m = 0; m < 4; m++) {
        short8 af = *(const short8*)(relcat + (rt * 32 + l31) * 64 + m * 16 + hi * 8);
        cr = __builtin_amdgcn_mfma_f32_32x32x16_bf16(af, qf[m], cr, 0, 0, 0);
      }
      __builtin_amdgcn_s_setprio(0);
      #pragma unroll
      for (int t = 0; t < 8; t++) {
        int rr = rt * 32 + ((2 * t) & 3) + 8 * (t >> 1) + 4 * hi;
        *(unsigned int*)&RB[l31 * 64 + rr] = pkbf(cr[2 * t], cr[2 * t + 1]);
      }
    }
    __builtin_amdgcn_wave_barrier();
    int qi = qrow / 14, qj = qrow - qi * 14;
    short8 qrel[2];
    #pragma unroll
    for (int m2 = 0; m2 < 2; m2++)
      #pragma unroll
      for (int j = 0; j < 8; j++) {
        int cc = m2 * 16 + hi * 8 + j;
        unsigned short vv = 0;
        if (cc < 14) vv = RB[l31 * 64 + (qi - cc + 13)];
        else if (cc < 28) vv = RB[l31 * 64 + 27 + (qj - (cc - 14) + 13)];
        qrel[m2][j] = (short)vv;
      }
    __builtin_amdgcn_wave_barrier();
    f32x16 olo = {}, ohi_ = {};
    float m_reg = -3e38f, s_run = 0.f;
    for (int kk = 0; kk < 6; kk++)
      attn_chunk<false>(kk, l31, hi, kg, VT, qf, qrel, olo, ohi_, m_reg, s_run);
    attn_chunk<true>(6, l31, hi, kg, VT, qf, qrel, olo, ohi_, m_reg, s_run);
    s_run += __shfl_xor(s_run, 32);
    float inv = 1.f / s_run;
    #pragma unroll
    for (int r = 0; r < 16; r++) {
      int qr = (r & 3) + 8 * (r >> 2) + 4 * hi;
      float ir = __shfl(inv, qr);
      int tok = q0 + qr;
      if (tok < 196) {
        size_t base = ((size_t)w * NTOK + tok) * DIMC + h * 64;
        attnout[base + l31] = f2bf(olo[r] * ir);
        attnout[base + 32 + l31] = f2bf(ohi_[r] * ir);
      }
    }
  }
}

extern "C" void kernel_launch(void* const* d_in, const int* in_sizes, int n_in,
                              void* d_out, int out_size, void* d_ws, size_t ws_size,
                              hipStream_t stream) {
  const float* x     = (const float*)d_in[0];
  const float* ln1w  = (const float*)d_in[1];
  const float* ln1b  = (const float*)d_in[2];
  const float* qkvw  = (const float*)d_in[3];
  const float* qkvb  = (const float*)d_in[4];
  const float* projw = (const float*)d_in[5];
  const float* projb = (const float*)d_in[6];
  const float* relh  = (const float*)d_in[7];
  const float* relw  = (const float*)d_in[8];
  const float* ln2w  = (const float*)d_in[9];
  const float* ln2b  = (const float*)d_in[10];
  const float* fc1w  = (const float*)d_in[11];
  const float* fc1b  = (const float*)d_in[12];
  const float* fc2w  = (const float*)d_in[13];
  const float* fc2b  = (const float*)d_in[14];

  const size_t R0 = 0;
  const size_t R1 = R0 + 50331648;
  const size_t R2 = R1 + 100663296;
  const size_t R3 = R2 + 30408704;
  const size_t NEED = R3 + 3547136;
  if (ws_size < NEED) return;
  char* ws = (char*)d_ws;
  unsigned short* xw     = (unsigned short*)(ws + R0);
  unsigned short* x2b    = (unsigned short*)(ws + R0);
  unsigned short* qk_g   = (unsigned short*)(ws + R1);
  unsigned short* vT_g   = qk_g + (size_t)2 * NWH * NTOK * 64;
  unsigned short* hidden = (unsigned short*)(ws + R1);
  unsigned short* attno  = (unsigned short*)(ws + R2);
  unsigned short* h2     = (unsigned short*)(ws + R2);
  unsigned short* qkvwT  = (unsigned short*)(ws + R3);
  unsigned short* projwT = qkvwT + 442368;
  unsigned short* fc1wT  = projwT + 147456;
  unsigned short* fc2wT  = fc1wT + 589824;
  unsigned short* relcat = fc2wT + 589824;

  pre_kernel<<<LN1BLKS + 7828, 256, 0, stream>>>(x, ln1w, ln1b, qkvw, projw, fc1w, fc2w,
                                                 relh, relw, xw, qkvwT, projwT, fc1wT,
                                                 fc2wT, relcat, vT_g);
  gemm_kernel<0, 256><<<dim3(154, 9), 256, 0, stream>>>(xw, qkvwT, MWIN, 384, qkvb,
                                                        nullptr, nullptr, nullptr, qk_g, vT_g);
  attn32_kernel<<<dim3(NWH, 2), 256, 0, stream>>>(qk_g, vT_g, relcat, attno);
  gemm_kernel<1, 128><<<dim3(307, 3), 256, 0, stream>>>(attno, projwT, MWIN, 384, projb,
                                                        x, nullptr, nullptr, x2b, nullptr);
  ln2_kernel<<<8192, 256, 0, stream>>>(x2b, ln2w, ln2b, h2);
  gemm_kernel<2, 256><<<dim3(128, 12), 256, 0, stream>>>(h2, fc1wT, MX, 384, fc1b,
                                                         nullptr, nullptr, nullptr, hidden, nullptr);
  gemm_kernel<3, 128><<<dim3(256, 3), 256, 0, stream>>>(hidden, fc2wT, MX, 1536, fc2b,
                                                        nullptr, x2b, (float*)d_out, nullptr, nullptr);
}

// Round 16
// 340.365 us; speedup vs baseline: 1.2442x; 1.2442x over previous
//
#include <hip/hip_runtime.h>
#include <math.h>

#define DIMC 384
#define NHD  6
#define HD   64
#define WSZ  14
#define NTOK 196
#define NWIN 200
#define NWH  1200
#define MWIN 39200
#define MX   32768
#define MLPD 1536

typedef short short8 __attribute__((ext_vector_type(8)));
typedef float f32x4 __attribute__((ext_vector_type(4)));
typedef float f32x16 __attribute__((ext_vector_type(16)));

__device__ __forceinline__ unsigned short f2bf(float f) {
  unsigned int u = __float_as_uint(f);
  u = (u + 0x7fffu + ((u >> 16) & 1u)) >> 16;
  return (unsigned short)u;
}
__device__ __forceinline__ float bf2f(unsigned int u) {
  return __uint_as_float(u << 16);
}
__device__ __forceinline__ unsigned int pkbf(float a, float b) {
  unsigned int r; asm("v_cvt_pk_bf16_f32 %0, %1, %2" : "=v"(r) : "v"(a), "v"(b)); return r;
}
// tanh-GELU (|err| <= ~3e-3 abs; well under tolerance here)
__device__ __forceinline__ float gelu_t(float x) {
  float z = 1.5957691216057308f * (x + 0.044715f * x * x * x);
  float e = __expf(z);
  float th = 1.f - 2.f * __builtin_amdgcn_rcpf(e + 1.f);
  return 0.5f * x * (1.f + th);
}

typedef const __attribute__((address_space(1))) unsigned int* gptr_t;
typedef __attribute__((address_space(3))) unsigned int* lptr_t;
__device__ __forceinline__ void gload16(const unsigned short* g, unsigned short* l) {
  __builtin_amdgcn_global_load_lds((gptr_t)(const void*)g, (lptr_t)(void*)l, 16, 0, 0);
}

// ---------- merged pre: LN1+window (4 tokens/block) THEN prep segments ----------
#define LN1BLKS 9800         // 39200 tokens / 4
#define SEG0 442368          // qkvwT  (K=384,  N=1152)
#define SEG1 589824          // projwT (K=384,  N=384)
#define SEG2 1179648         // fc1wT  (K=384,  N=1536)
#define SEG3 1769472         // fc2wT  (K=1536, N=384)
#define SEG4 1773568         // relcat (4096)
#define SEG5 2003968         // vpad   (76800*3 int2 writes)
__global__ __launch_bounds__(256) void pre_kernel(
    const float* __restrict__ x, const float* __restrict__ ln1w, const float* __restrict__ ln1b,
    const float* __restrict__ qkvw, const float* __restrict__ projw,
    const float* __restrict__ fc1w, const float* __restrict__ fc2w,
    const float* __restrict__ relh, const float* __restrict__ relw,
    unsigned short* __restrict__ xw,
    unsigned short* __restrict__ qkvwT, unsigned short* __restrict__ projwT,
    unsigned short* __restrict__ fc1wT, unsigned short* __restrict__ fc2wT,
    unsigned short* __restrict__ relcat, unsigned short* __restrict__ vT) {
  const int blk = blockIdx.x;
  if (blk < LN1BLKS) {
    int t = blk * 4 + (threadIdx.x >> 6);
    int lane = threadIdx.x & 63;
    int win = t / NTOK, p = t - win * NTOK;
    int bb = win / 25, rem = win - bb * 25;
    int wi = rem / 5, wj = rem - wi * 5;
    int i = p / WSZ, j = p - i * WSZ;
    int r = wi * WSZ + i, c = wj * WSZ + j;
    unsigned short* o = xw + (size_t)t * DIMC;
    if (r >= 64 || c >= 64) {
      #pragma unroll
      for (int q = 0; q < 6; q++) o[lane + q * 64] = 0;
      return;
    }
    const float* xr = x + (((size_t)bb * 64 + r) * 64 + c) * DIMC;
    float v[6]; float s = 0.f, s2 = 0.f;
    #pragma unroll
    for (int q = 0; q < 6; q++) { float f = xr[lane + q * 64]; v[q] = f; s += f; s2 += f * f; }
    #pragma unroll
    for (int off = 32; off; off >>= 1) { s += __shfl_xor(s, off); s2 += __shfl_xor(s2, off); }
    float mean = s * (1.f / DIMC);
    float var  = s2 * (1.f / DIMC) - mean * mean;
    float rstd = rsqrtf(var + 1e-5f);
    #pragma unroll
    for (int q = 0; q < 6; q++) {
      int d = lane + q * 64;
      o[d] = f2bf((v[q] - mean) * rstd * ln1w[d] + ln1b[d]);
    }
    return;
  }
  int id = (blk - LN1BLKS) * 256 + threadIdx.x;
  if (id < SEG0) {
    int n = id / 384, k = id - n * 384;
    qkvwT[id] = f2bf(qkvw[(size_t)k * 1152 + n]);
  } else if (id < SEG1) {
    id -= SEG0;
    int n = id / 384, k = id - n * 384;
    projwT[id] = f2bf(projw[(size_t)k * 384 + n]);
  } else if (id < SEG2) {
    id -= SEG1;
    int n = id / 384, k = id - n * 384;
    fc1wT[id] = f2bf(fc1w[(size_t)k * 1536 + n]);
  } else if (id < SEG3) {
    id -= SEG2;
    int n = id / 1536, k = id - n * 1536;
    fc2wT[id] = f2bf(fc2w[(size_t)k * 384 + n]);
  } else if (id < SEG4) {
    id -= SEG3;
    int rc = id >> 6, d = id & 63;
    float v = 0.f;
    if (rc < 27) v = relh[rc * 64 + d] * 8.f;
    else if (rc < 54) v = relw[(rc - 27) * 64 + d] * 8.f;
    relcat[id] = f2bf(v);
  } else if (id < SEG5) {
    id -= SEG4;
    int row = id / 3, part = id - row * 3;
    *(int2*)(vT + (size_t)row * 208 + 196 + part * 4) = make_int2(0, 0);
  }
}

// ---------- LN2: 4 rows per 256-thr block, x2 in bf16 ----------
__global__ __launch_bounds__(256) void ln2_kernel(const unsigned short* __restrict__ x2b,
    const float* __restrict__ w, const float* __restrict__ b, unsigned short* __restrict__ h2) {
  int t = blockIdx.x * 4 + (threadIdx.x >> 6);
  int lane = threadIdx.x & 63;
  const unsigned short* xr = x2b + (size_t)t * DIMC;
  unsigned short* o = h2 + (size_t)t * DIMC;
  float v[6]; float s = 0.f, s2 = 0.f;
  #pragma unroll
  for (int q = 0; q < 6; q++) { float f = bf2f(xr[lane + q * 64]); v[q] = f; s += f; s2 += f * f; }
  #pragma unroll
  for (int off = 32; off; off >>= 1) { s += __shfl_xor(s, off); s2 += __shfl_xor(s2, off); }
  float mean = s * (1.f / DIMC);
  float var  = s2 * (1.f / DIMC) - mean * mean;
  float rstd = rsqrtf(var + 1e-5f);
  #pragma unroll
  for (int q = 0; q < 6; q++) {
    int d = lane + q * 64;
    o[d] = f2bf((v[q] - mean) * rstd * w[d] + b[d]);
  }
}

// ---------- bf16 MFMA GEMM: 128x128, 3-buffer counted-vmcnt pipeline, swizzled LDS,
// XCD remap. (proven best configuration.) ----------
// EPI 0: qkv  -> q,k bf16 packed; v transposed scatter
// EPI 1: proj -> (acc+bias+x_f32) -> x2 bf16 packed
// EPI 2: fc1  -> bias + gelu -> hidden bf16 packed
// EPI 3: fc2  -> bias + x2(bf16) residual -> d_out fp32
template <int EPI>
__global__ __launch_bounds__(256) void gemm_kernel(
    const unsigned short* __restrict__ A, const unsigned short* __restrict__ WT,
    int Mrows, int Kd,
    const float* __restrict__ bias,
    const float* __restrict__ addinf, const unsigned short* __restrict__ addinb,
    float* __restrict__ outf, unsigned short* __restrict__ outb,
    unsigned short* __restrict__ outb2) {
  __shared__ unsigned short As[3][128 * 32];
  __shared__ unsigned short Bs[3][128 * 32];
  const int nwg = gridDim.x * gridDim.y;
  const int flat = blockIdx.y * gridDim.x + blockIdx.x;
  const int xcd = flat & 7, q_ = nwg >> 3, r_ = nwg & 7;
  const int wg = (xcd < r_ ? xcd * (q_ + 1) : r_ * (q_ + 1) + (xcd - r_) * q_) + (flat >> 3);
  const int bx = wg / gridDim.y, by = wg - bx * gridDim.y;
  const int row0 = bx * 128, col0 = by * 128;
  const int tid = threadIdx.x;
  const int l = tid & 63, wid = tid >> 6;
  const int fr = l & 15, fk = (l >> 4) * 8;
  const int wr = (wid >> 1) * 64, wc = (wid & 1) * 64;
  const int sr = l >> 2, sc = (l & 3) * 8;
  const int scs = sc ^ (((sr >> 1) & 3) << 3);
  const int rsw = ((fr >> 1) & 3) << 3;
  f32x4 acc[4][4] = {};
  const unsigned short* ap = A + (size_t)row0 * Kd;
  const unsigned short* bp = WT + (size_t)col0 * Kd;
  const int nt = Kd >> 5;

  auto stage = [&](int t, int b) {
    const int k0 = t * 32;
    #pragma unroll
    for (int j = 0; j < 2; j++) {
      int chunk = j * 4 + wid;
      gload16(ap + (size_t)(chunk * 16 + sr) * Kd + k0 + scs, &As[b][chunk * 512]);
      gload16(bp + (size_t)(chunk * 16 + sr) * Kd + k0 + scs, &Bs[b][chunk * 512]);
    }
  };
  stage(0, 0);
  stage(1, 1);
  int c = 0;
  for (int t = 0; t < nt; ++t) {
    if (t < nt - 1) asm volatile("s_waitcnt vmcnt(4)" ::: "memory");
    else            asm volatile("s_waitcnt vmcnt(0)" ::: "memory");
    __builtin_amdgcn_s_barrier();
    __builtin_amdgcn_sched_barrier(0);
    if (t + 2 < nt) stage(t + 2, (c + 2 >= 3) ? c - 1 : c + 2);
    short8 a[4], b[4];
    #pragma unroll
    for (int fi = 0; fi < 4; fi++) {
      a[fi] = *(const short8*)&As[c][(wr + fi * 16 + fr) * 32 + (fk ^ rsw)];
      b[fi] = *(const short8*)&Bs[c][(wc + fi * 16 + fr) * 32 + (fk ^ rsw)];
    }
    __builtin_amdgcn_s_setprio(1);
    #pragma unroll
    for (int fi = 0; fi < 4; fi++)
      #pragma unroll
      for (int fj = 0; fj < 4; fj++)
        acc[fi][fj] = __builtin_amdgcn_mfma_f32_16x16x32_bf16(b[fj], a[fi], acc[fi][fj], 0, 0, 0);
    __builtin_amdgcn_s_setprio(0);
    c = (c + 1 >= 3) ? 0 : c + 1;
  }
  #pragma unroll
  for (int fi = 0; fi < 4; fi++) {
    const int gr = row0 + wr + fi * 16 + fr;
    if (gr >= Mrows) continue;
    int wv_ = 0, p = 0, valid = 1; size_t pixbase = 0;
    if (EPI == 0 || EPI == 1) { wv_ = gr / NTOK; p = gr - wv_ * NTOK; }
    if (EPI == 1) {
      int bb = wv_ / 25, rem2 = wv_ - bb * 25;
      int wi = rem2 / 5, wj = rem2 - wi * 5;
      int i = p / WSZ, j = p - i * WSZ;
      int rr = wi * WSZ + i, cc = wj * WSZ + j;
      valid = (rr < 64) && (cc < 64);
      pixbase = (((size_t)bb * 64 + rr) * 64 + cc) * DIMC;
    }
    #pragma unroll
    for (int fj = 0; fj < 4; fj++) {
      const int gcb = col0 + wc + fj * 16 + (l >> 4) * 4;
      f32x4 v = acc[fi][fj];
      float4 bv = *(const float4*)&bias[gcb];
      float t0 = v[0] + bv.x, t1 = v[1] + bv.y, t2 = v[2] + bv.z, t3 = v[3] + bv.w;
      if (EPI == 0) {
        int s = gcb / 384, rem = gcb - s * 384;
        int hh = rem >> 6, d0 = gcb & 63;
        int whh = wv_ * NHD + hh;
        if (s == 0) { t0 *= 0.125f; t1 *= 0.125f; t2 *= 0.125f; t3 *= 0.125f; }
        if (s < 2) {
          *(int2*)&outb[((size_t)s * NWH + whh) * (NTOK * 64) + p * 64 + d0] =
              make_int2((int)pkbf(t0, t1), (int)pkbf(t2, t3));
        } else {
          unsigned short* vb = outb2 + ((size_t)whh * 64 + d0) * 208 + p;
          vb[0] = f2bf(t0); vb[208] = f2bf(t1); vb[416] = f2bf(t2); vb[624] = f2bf(t3);
        }
      } else if (EPI == 1) {
        if (valid) {
          size_t idx = pixbase + gcb;
          float4 ad = *(const float4*)&addinf[idx];
          *(int2*)&outb[idx] = make_int2((int)pkbf(t0 + ad.x, t1 + ad.y),
                                         (int)pkbf(t2 + ad.z, t3 + ad.w));
        }
      } else if (EPI == 2) {
        *(int2*)&outb[(size_t)gr * MLPD + gcb] =
            make_int2((int)pkbf(gelu_t(t0), gelu_t(t1)), (int)pkbf(gelu_t(t2), gelu_t(t3)));
      } else {
        size_t idx = (size_t)gr * DIMC + gcb;
        int2 adp = *(const int2*)&addinb[idx];
        unsigned int u0 = (unsigned int)adp.x, u1 = (unsigned int)adp.y;
        float4 o = make_float4(t0 + bf2f(u0 & 0xffffu), t1 + bf2f(u0 >> 16),
                               t2 + bf2f(u1 & 0xffffu), t3 + bf2f(u1 >> 16));
        *(float4*)&outf[idx] = o;
      }
    }
  }
}

// ---------- 32x32 MFMA attention: in-register P, defer-max online softmax ----------
template <bool TAIL>
__device__ __forceinline__ void attn_chunk(
    int kk, int l31, int hi,
    const unsigned short* __restrict__ kg,
    const unsigned short* __restrict__ VT,
    const short8* qf, const short8* qrel,
    f32x16& olo, f32x16& ohi_, float& m_reg, float& s_run) {
  int key = kk * 32 + l31;
  int keyc = (TAIL && key > 195) ? 195 : key;
  f32x16 S = {};
  __builtin_amdgcn_s_setprio(1);
  #pragma unroll
  for (int m = 0; m < 4; m++) {
    short8 kf = *(const short8*)(kg + (size_t)keyc * 64 + m * 16 + hi * 8);
    S = __builtin_amdgcn_mfma_f32_32x32x16_bf16(kf, qf[m], S, 0, 0, 0);
  }
  {
    int ki = keyc / 14, kj = keyc - ki * 14;
    #pragma unroll
    for (int m2 = 0; m2 < 2; m2++) {
      short8 kh;
      #pragma unroll
      for (int j = 0; j < 8; j++) {
        int cc = m2 * 16 + hi * 8 + j;
        kh[j] = (short)((cc == ki || cc == 14 + kj) ? 0x3F80 : 0);
      }
      S = __builtin_amdgcn_mfma_f32_32x32x16_bf16(kh, qrel[m2], S, 0, 0, 0);
    }
  }
  __builtin_amdgcn_s_setprio(0);
  float pmax = -3e38f;
  #pragma unroll
  for (int r = 0; r < 16; r++) {
    if (TAIL) {
      int krow = kk * 32 + (r & 3) + 8 * (r >> 2) + 4 * hi;
      if (krow >= 196) S[r] = -3e38f;
    }
    pmax = fmaxf(pmax, S[r]);
  }
  pmax = fmaxf(pmax, __shfl_xor(pmax, 32));
  if (__any(pmax > m_reg + 8.f)) {
    float m_new = fmaxf(m_reg, pmax);
    float fac = __expf(m_reg - m_new);
    m_reg = m_new;
    s_run *= fac;
    #pragma unroll
    for (int r = 0; r < 16; r++) {
      int qr = (r & 3) + 8 * (r >> 2) + 4 * hi;
      float fr_ = __shfl(fac, qr);
      olo[r] *= fr_; ohi_[r] *= fr_;
    }
  }
  float psum = 0.f;
  #pragma unroll
  for (int r = 0; r < 16; r++) { S[r] = __expf(S[r] - m_reg); psum += S[r]; }
  s_run += psum;
  unsigned int pk[8];
  #pragma unroll
  for (int t = 0; t < 8; t++) pk[t] = pkbf(S[2 * t], S[2 * t + 1]);
  #pragma unroll
  for (int m2 = 0; m2 < 2; m2++) {
    int b_ = m2 * 4;
    unsigned int x0 = (unsigned int)__shfl_xor((int)pk[b_ + 0], 32);
    unsigned int x1 = (unsigned int)__shfl_xor((int)pk[b_ + 1], 32);
    unsigned int x2 = (unsigned int)__shfl_xor((int)pk[b_ + 2], 32);
    unsigned int x3 = (unsigned int)__shfl_xor((int)pk[b_ + 3], 32);
    unsigned int au[4];
    au[0] = hi ? x2 : pk[b_ + 0];
    au[1] = hi ? x3 : pk[b_ + 1];
    au[2] = hi ? pk[b_ + 2] : x0;
    au[3] = hi ? pk[b_ + 3] : x1;
    short8 pa; __builtin_memcpy(&pa, au, 16);
    int kb = kk * 32 + m2 * 16 + hi * 8;
    if (TAIL && kb > 208) kb = 208;
    short8 vblo = *(const short8*)&VT[l31 * 216 + kb];
    short8 vbhi = *(const short8*)&VT[(32 + l31) * 216 + kb];
    __builtin_amdgcn_s_setprio(1);
    olo  = __builtin_amdgcn_mfma_f32_32x32x16_bf16(pa, vblo, olo, 0, 0, 0);
    ohi_ = __builtin_amdgcn_mfma_f32_32x32x16_bf16(pa, vbhi, ohi_, 0, 0, 0);
    __builtin_amdgcn_s_setprio(0);
  }
}

__global__ __launch_bounds__(256) void attn32_kernel(
    const unsigned short* __restrict__ qk_g,
    const unsigned short* __restrict__ vT_g,
    const unsigned short* __restrict__ relcat,
    unsigned short* __restrict__ attnout) {
  __shared__ __align__(16) unsigned short VT[64 * 216];
  __shared__ __align__(16) unsigned short RELB[4][2048];
  const int wh = blockIdx.x, y = blockIdx.y;
  const int w = wh / NHD, h = wh - w * NHD;
  const int tid = threadIdx.x;
  const unsigned short* vrow = vT_g + (size_t)wh * 64 * 208;
  for (int e = tid; e < 64 * 27; e += 256) {
    int d = e / 27, c = e - d * 27;
    int4 val = {0, 0, 0, 0};
    if (c < 26) val = *(const int4*)(vrow + d * 208 + c * 8);
    *(int4*)&VT[d * 216 + c * 8] = val;
  }
  __syncthreads();
  const int l = tid & 63, wv = tid >> 6;
  const int l31 = l & 31, hi = l >> 5;
  unsigned short* RB = &RELB[wv][0];
  const unsigned short* qg = qk_g + (size_t)wh * (NTOK * 64);
  const unsigned short* kg = qk_g + (size_t)(NWH + wh) * (NTOK * 64);

  const int tbeg = y ? 4 : 0, tend = y ? 7 : 4;
  for (int tile = tbeg + wv; tile < tend; tile += 4) {
    const int q0 = tile * 32;
    int qrow = q0 + l31; if (qrow > 195) qrow = 195;
    short8 qf[4];
    #pragma unroll
    for (int m = 0; m < 4; m++)
      qf[m] = *(const short8*)(qg + (size_t)qrow * 64 + m * 16 + hi * 8);
    #pragma unroll
    for (int rt = 0; rt < 2; rt++) {
      f32x16 cr = {};
      __builtin_amdgcn_s_setprio(1);
      #pragma unroll
      for (int m = 0; m < 4; m++) {
        short8 af = *(const short8*)(relcat + (rt * 32 + l31) * 64 + m * 16 + hi * 8);
        cr = __builtin_amdgcn_mfma_f32_32x32x16_bf16(af, qf[m], cr, 0, 0, 0);
      }
      __builtin_amdgcn_s_setprio(0);
      #pragma unroll
      for (int t = 0; t < 8; t++) {
        int rr = rt * 32 + ((2 * t) & 3) + 8 * (t >> 1) + 4 * hi;
        *(unsigned int*)&RB[l31 * 64 + rr] = pkbf(cr[2 * t], cr[2 * t + 1]);
      }
    }
    __builtin_amdgcn_wave_barrier();
    int qi = qrow / 14, qj = qrow - qi * 14;
    short8 qrel[2];
    #pragma unroll
    for (int m2 = 0; m2 < 2; m2++)
      #pragma unroll
      for (int j = 0; j < 8; j++) {
        int cc = m2 * 16 + hi * 8 + j;
        unsigned short vv = 0;
        if (cc < 14) vv = RB[l31 * 64 + (qi - cc + 13)];
        else if (cc < 28) vv = RB[l31 * 64 + 27 + (qj - (cc - 14) + 13)];
        qrel[m2][j] = (short)vv;
      }
    __builtin_amdgcn_wave_barrier();
    f32x16 olo = {}, ohi_ = {};
    float m_reg = -3e38f, s_run = 0.f;
    for (int kk = 0; kk < 6; kk++)
      attn_chunk<false>(kk, l31, hi, kg, VT, qf, qrel, olo, ohi_, m_reg, s_run);
    attn_chunk<true>(6, l31, hi, kg, VT, qf, qrel, olo, ohi_, m_reg, s_run);
    s_run += __shfl_xor(s_run, 32);
    float inv = 1.f / s_run;
    #pragma unroll
    for (int r = 0; r < 16; r++) {
      int qr = (r & 3) + 8 * (r >> 2) + 4 * hi;
      float ir = __shfl(inv, qr);
      int tok = q0 + qr;
      if (tok < 196) {
        size_t base = ((size_t)w * NTOK + tok) * DIMC + h * 64;
        attnout[base + l31] = f2bf(olo[r] * ir);
        attnout[base + 32 + l31] = f2bf(ohi_[r] * ir);
      }
    }
  }
}

extern "C" void kernel_launch(void* const* d_in, const int* in_sizes, int n_in,
                              void* d_out, int out_size, void* d_ws, size_t ws_size,
                              hipStream_t stream) {
  const float* x     = (const float*)d_in[0];
  const float* ln1w  = (const float*)d_in[1];
  const float* ln1b  = (const float*)d_in[2];
  const float* qkvw  = (const float*)d_in[3];
  const float* qkvb  = (const float*)d_in[4];
  const float* projw = (const float*)d_in[5];
  const float* projb = (const float*)d_in[6];
  const float* relh  = (const float*)d_in[7];
  const float* relw  = (const float*)d_in[8];
  const float* ln2w  = (const float*)d_in[9];
  const float* ln2b  = (const float*)d_in[10];
  const float* fc1w  = (const float*)d_in[11];
  const float* fc1b  = (const float*)d_in[12];
  const float* fc2w  = (const float*)d_in[13];
  const float* fc2b  = (const float*)d_in[14];

  const size_t R0 = 0;
  const size_t R1 = R0 + 50331648;
  const size_t R2 = R1 + 100663296;
  const size_t R3 = R2 + 30408704;
  const size_t NEED = R3 + 3547136;
  if (ws_size < NEED) return;
  char* ws = (char*)d_ws;
  unsigned short* xw     = (unsigned short*)(ws + R0);
  unsigned short* x2b    = (unsigned short*)(ws + R0);
  unsigned short* qk_g   = (unsigned short*)(ws + R1);
  unsigned short* vT_g   = qk_g + (size_t)2 * NWH * NTOK * 64;
  unsigned short* hidden = (unsigned short*)(ws + R1);
  unsigned short* attno  = (unsigned short*)(ws + R2);
  unsigned short* h2     = (unsigned short*)(ws + R2);
  unsigned short* qkvwT  = (unsigned short*)(ws + R3);
  unsigned short* projwT = qkvwT + 442368;
  unsigned short* fc1wT  = projwT + 147456;
  unsigned short* fc2wT  = fc1wT + 589824;
  unsigned short* relcat = fc2wT + 589824;

  pre_kernel<<<LN1BLKS + 7828, 256, 0, stream>>>(x, ln1w, ln1b, qkvw, projw, fc1w, fc2w,
                                                 relh, relw, xw, qkvwT, projwT, fc1wT,
                                                 fc2wT, relcat, vT_g);
  gemm_kernel<0><<<dim3(307, 9), 256, 0, stream>>>(xw, qkvwT, MWIN, 384, qkvb,
                                                   nullptr, nullptr, nullptr, qk_g, vT_g);
  attn32_kernel<<<dim3(NWH, 2), 256, 0, stream>>>(qk_g, vT_g, relcat, attno);
  gemm_kernel<1><<<dim3(307, 3), 256, 0, stream>>>(attno, projwT, MWIN, 384, projb,
                                                   x, nullptr, nullptr, x2b, nullptr);
  ln2_kernel<<<8192, 256, 0, stream>>>(x2b, ln2w, ln2b, h2);
  gemm_kernel<2><<<dim3(256, 12), 256, 0, stream>>>(h2, fc1wT, MX, 384, fc1b,
                                                    nullptr, nullptr, nullptr, hidden, nullptr);
  gemm_kernel<3><<<dim3(256, 3), 256, 0, stream>>>(hidden, fc2wT, MX, 1536, fc2b,
                                                   nullptr, x2b, (float*)d_out, nullptr, nullptr);
}